// Round 8
// baseline (129.110 us; speedup 1.0000x reference)
//
#include <hip/hip_runtime.h>
#include <math.h>

#define NG      1024
#define IMG_H   128
#define IMG_W   128
#define NPIX    (IMG_H * IMG_W)
#define MIN_A   (1.0f / 255.0f)
#define LOG2E   1.4426950408889634f
#define REPS    12          // diagnostic amplification of the composite phase

// Record layout (per gaussian, sorted by z):
//  g0 = {mx, my, a2, b2}          a2 = -0.5*conicA*log2e, b2 = -conicB*log2e
//  g1 = {c2, op_eff, colR, colG}  c2 = -0.5*conicC*log2e
//  g2 = colB
// G = exp2( min(a2*dx^2 + c2*dy^2 + b2*dx*dy, 0) )

// ---------------------------------------------------------------------------
__device__ inline void project_one(
    int i,
    const float* __restrict__ pos, const float* __restrict__ cov,
    const float* __restrict__ col, const float* __restrict__ opa,
    const float* __restrict__ cm,
    float4& r0, float4& r1, float& r2)
{
    const float R00 = cm[0], R01 = cm[1], R02 = cm[2],  T0 = cm[3];
    const float R10 = cm[4], R11 = cm[5], R12 = cm[6],  T1 = cm[7];
    const float R20 = cm[8], R21 = cm[9], R22 = cm[10], T2 = cm[11];

    const float p0 = pos[3*i], p1 = pos[3*i+1], p2 = pos[3*i+2];
    const float x = R00*p0 + R01*p1 + R02*p2 + T0;
    const float y = R10*p0 + R11*p1 + R12*p2 + T1;
    const float z = R20*p0 + R21*p1 + R22*p2 + T2;

    const float focal = 110.85125168440814f;   // 0.5*128/tan(pi/6)
    const float zc = fmaxf(z, 1e-6f);
    const float mx = focal * x / zc + 0.5f * IMG_W;
    const float my = focal * y / zc + 0.5f * IMG_H;

    const float c00 = cov[9*i+0], c01 = cov[9*i+1], c02 = cov[9*i+2];
    const float c10 = cov[9*i+3], c11 = cov[9*i+4], c12 = cov[9*i+5];
    const float c20 = cov[9*i+6], c21 = cov[9*i+7], c22 = cov[9*i+8];
    const float s00 = c00, s01 = 0.5f*(c01+c10), s02 = 0.5f*(c02+c20);
    const float s11 = c11, s12 = 0.5f*(c12+c21), s22 = c22;

    const float RS00 = R00*s00 + R01*s01 + R02*s02;
    const float RS01 = R00*s01 + R01*s11 + R02*s12;
    const float RS02 = R00*s02 + R01*s12 + R02*s22;
    const float RS10 = R10*s00 + R11*s01 + R12*s02;
    const float RS11 = R10*s01 + R11*s11 + R12*s12;
    const float RS12 = R10*s02 + R11*s12 + R12*s22;
    const float RS20 = R20*s00 + R21*s01 + R22*s02;
    const float RS21 = R20*s01 + R21*s11 + R22*s12;
    const float RS22 = R20*s02 + R21*s12 + R22*s22;
    const float CC00 = RS00*R00 + RS01*R01 + RS02*R02;
    const float CC01 = RS00*R10 + RS01*R11 + RS02*R12;
    const float CC02 = RS00*R20 + RS01*R21 + RS02*R22;
    const float CC11 = RS10*R10 + RS11*R11 + RS12*R12;
    const float CC12 = RS10*R20 + RS11*R21 + RS12*R22;
    const float CC20 = RS20*R00 + RS21*R01 + RS22*R02;
    const float CC21 = RS20*R10 + RS21*R11 + RS22*R12;
    const float CC22 = RS20*R20 + RS21*R21 + RS22*R22;

    const float j00 = focal / zc, j02 = -focal * x / (zc*zc);
    const float j11 = focal / zc, j12 = -focal * y / (zc*zc);

    const float v00 = CC00*j00 + CC02*j02;
    const float v02 = CC20*j00 + CC22*j02;
    const float v10 = CC01*j11 + CC02*j12;
    const float v11 = CC11*j11 + CC12*j12;
    const float v12 = CC21*j11 + CC22*j12;

    const float a  = j00*v00 + j02*v02 + 0.3f;
    const float b  = j00*v10 + j02*v12;
    const float cQ = j11*v11 + j12*v12 + 0.3f;

    const float det = a*cQ - b*b;
    const float det_safe = (det > 0.f) ? det : 1.f;
    const float conA =  cQ / det_safe;
    const float conB = -b  / det_safe;
    const float conC =  a  / det_safe;

    const bool  valid  = (z > 0.2f) && (det > 0.f);
    const float op_eff = valid ? opa[i] : 0.f;

    r0 = make_float4(mx, my, -0.5f*conA*LOG2E, -conB*LOG2E);
    r1 = make_float4(-0.5f*conC*LOG2E, op_eff, col[3*i], col[3*i+1]);
    r2 = col[3*i+2];
}

// ---------------------------------------------------------------------------
// Kernel 1: fused project + stable rank-sort + scatter (16 blocks x 64).
// ---------------------------------------------------------------------------
__global__ __launch_bounds__(64) void gs_prep(
    const float* __restrict__ pos, const float* __restrict__ cov,
    const float* __restrict__ col, const float* __restrict__ opa,
    const float* __restrict__ cm,
    float4* __restrict__ g0, float4* __restrict__ g1, float* __restrict__ g2)
{
    __shared__ float4 zsh4[NG / 4];
    float* zsh = (float*)zsh4;

    const int tid = threadIdx.x;
    const float R20 = cm[8], R21 = cm[9], R22 = cm[10], T2 = cm[11];

    #pragma unroll
    for (int q = 0; q < NG / 64; ++q) {
        const int g = q * 64 + tid;
        zsh[g] = R20*pos[3*g] + R21*pos[3*g+1] + R22*pos[3*g+2] + T2;
    }
    __syncthreads();

    const int i = blockIdx.x * 64 + tid;
    float4 r0, r1; float r2;
    project_one(i, pos, cov, col, opa, cm, r0, r1, r2);

    const float zi = zsh[i];
    int rank = 0;
    #pragma unroll 4
    for (int j4 = 0; j4 < NG / 4; ++j4) {
        const float4 v = zsh4[j4];
        const int j = 4 * j4;
        rank += (v.x < zi || (v.x == zi && j + 0 < i)) ? 1 : 0;
        rank += (v.y < zi || (v.y == zi && j + 1 < i)) ? 1 : 0;
        rank += (v.z < zi || (v.z == zi && j + 2 < i)) ? 1 : 0;
        rank += (v.w < zi || (v.w == zi && j + 3 < i)) ? 1 : 0;
    }
    g0[rank] = r0; g1[rank] = r1; g2[rank] = r2;
}

// ---------------------------------------------------------------------------
// Kernel 2 (DIAGNOSTIC, x12 amplified): LDS-record chunked raster + combine.
// 256 blocks x 1024 threads, 1 block/CU. All 36 KB of records staged in LDS
// once; the composite phase (thread (c,jj): chunk c of 16 gaussians x 4
// pixels) is repeated REPS times with identical results (accumulators reset
// each rep; kept live via empty asm so reps can't be DCE'd). Final rep's
// values are written. Amplification makes this kernel dominate the profile
// so its counters (VALUBusy / FETCH / conflicts / occupancy) become visible
// past the harness's ~40us fillBuffer dispatches.
// ---------------------------------------------------------------------------
__global__ __launch_bounds__(1024) void gs_raster_lds(
    const float4* __restrict__ g0, const float4* __restrict__ g1,
    const float*  __restrict__ g2, float* __restrict__ out)
{
    __shared__ float4 s0[NG];            // 16 KB
    __shared__ float4 s1[NG];            // 16 KB
    __shared__ float  s2[NG];            //  4 KB
    __shared__ float4 part[64 * 64];     // 64 KB  [chunk][pixel]

    const int tid = threadIdx.x;
    s0[tid] = g0[tid];
    s1[tid] = g1[tid];
    s2[tid] = g2[tid];
    __syncthreads();

    const int c  = tid >> 4;             // chunk 0..63 (16 gaussians each)
    const int jj = tid & 15;
    const int pxbase = blockIdx.x * 64;

    float pxf[4], pyf[4];
    #pragma unroll
    for (int m = 0; m < 4; ++m) {
        const int p = pxbase + jj + m * 16;
        pxf[m] = (float)(p & (IMG_W - 1)) + 0.5f;
        pyf[m] = (float)(p >> 7) + 0.5f;
    }

    float T[4], cr[4], cg_[4], cb[4];
    const int base = c * 16;

    for (int rep = 0; rep < REPS; ++rep) {
        #pragma unroll
        for (int m = 0; m < 4; ++m) { T[m] = 1.f; cr[m] = 0.f; cg_[m] = 0.f; cb[m] = 0.f; }

        #pragma unroll 4
        for (int i = 0; i < 16; ++i) {
            const float4 A = s0[base + i];   // mx, my, a2, b2
            const float4 B = s1[base + i];   // c2, op, colR, colG
            const float  C = s2[base + i];
            #pragma unroll
            for (int m = 0; m < 4; ++m) {
                const float dx = pxf[m] - A.x;
                const float dy = pyf[m] - A.y;
                const float pw = fminf(A.z*dx*dx + B.x*dy*dy + A.w*(dx*dy), 0.f);
                const float G = __builtin_amdgcn_exp2f(pw);
                float alpha = fminf(B.y * G, 0.99f);
                alpha = (alpha >= MIN_A) ? alpha : 0.f;
                const float wT = alpha * T[m];
                cr[m]  = fmaf(wT, B.z, cr[m]);
                cg_[m] = fmaf(wT, B.w, cg_[m]);
                cb[m]  = fmaf(wT, C,   cb[m]);
                T[m] *= (1.f - alpha);
            }
        }
        // keep every rep's results live (values unchanged) so reps aren't DCE'd
        #pragma unroll
        for (int m = 0; m < 4; ++m)
            asm volatile("" : "+v"(cr[m]), "+v"(cg_[m]), "+v"(cb[m]), "+v"(T[m]));
    }

    #pragma unroll
    for (int m = 0; m < 4; ++m)
        part[c * 64 + jj + m * 16] = make_float4(cr[m], cg_[m], cb[m], T[m]);

    __syncthreads();

    if (tid < 64) {                      // one thread per pixel: 64-chunk scan
        float Ts = 1.f, r = 0.f, g = 0.f, b = 0.f;
        #pragma unroll 8
        for (int k = 0; k < 64; ++k) {
            const float4 v = part[k * 64 + tid];
            r = fmaf(Ts, v.x, r);
            g = fmaf(Ts, v.y, g);
            b = fmaf(Ts, v.z, b);
            Ts *= v.w;
        }
        float* o = out + 3 * (pxbase + tid);
        o[0] = r; o[1] = g; o[2] = b;
    }
}

// ---------------------------------------------------------------------------
extern "C" void kernel_launch(void* const* d_in, const int* in_sizes, int n_in,
                              void* d_out, int out_size, void* d_ws, size_t ws_size,
                              hipStream_t stream) {
    const float* pos = (const float*)d_in[0];
    const float* cov = (const float*)d_in[1];
    const float* col = (const float*)d_in[2];
    const float* opa = (const float*)d_in[3];
    const float* cm  = (const float*)d_in[4];

    char* ws = (char*)d_ws;
    float4* g0 = (float4*)(ws);                 // 16384 B
    float4* g1 = (float4*)(ws + 16384);         // 16384 B
    float*  g2 = (float*) (ws + 32768);         //  4096 B

    gs_prep<<<NG / 64, 64, 0, stream>>>(pos, cov, col, opa, cm, g0, g1, g2);
    gs_raster_lds<<<NPIX / 64, 1024, 0, stream>>>(g0, g1, g2, (float*)d_out);
}

// Round 9
// 44.668 us; speedup vs baseline: 2.8904x; 2.8904x over previous
//
#include <hip/hip_runtime.h>
#include <math.h>

#define NG      1024
#define IMG_H   128
#define IMG_W   128
#define NPIX    (IMG_H * IMG_W)
#define MIN_A   (1.0f / 255.0f)
#define LOG2E   1.4426950408889634f

// Record layout (per gaussian, sorted by z):
//  g0 = {mx, my, a2, b2}          a2 = -0.5*conicA*log2e, b2 = -conicB*log2e
//  g1 = {c2, op_eff, colR, colG}  c2 = -0.5*conicC*log2e
//  g2 = colB
//  g3 = {mx, my, dxm, dym}        exact AABB of the alpha>=1/255 level set
//                                 (dxm<0 => never visible)
// G = exp2( min(a2*dx^2 + c2*dy^2 + b2*dx*dy, 0) )
// alpha >= 1/255  <=>  Q <= 2*ln(255*op); AABB halfwidths sqrt(s*(cov2d+0.3)ii)

// ---------------------------------------------------------------------------
__device__ inline void project_one(
    int i,
    const float* __restrict__ pos, const float* __restrict__ cov,
    const float* __restrict__ col, const float* __restrict__ opa,
    const float* __restrict__ cm,
    float4& r0, float4& r1, float& r2, float4& r3)
{
    const float R00 = cm[0], R01 = cm[1], R02 = cm[2],  T0 = cm[3];
    const float R10 = cm[4], R11 = cm[5], R12 = cm[6],  T1 = cm[7];
    const float R20 = cm[8], R21 = cm[9], R22 = cm[10], T2 = cm[11];

    const float p0 = pos[3*i], p1 = pos[3*i+1], p2 = pos[3*i+2];
    const float x = R00*p0 + R01*p1 + R02*p2 + T0;
    const float y = R10*p0 + R11*p1 + R12*p2 + T1;
    const float z = R20*p0 + R21*p1 + R22*p2 + T2;

    const float focal = 110.85125168440814f;   // 0.5*128/tan(pi/6)
    const float zc = fmaxf(z, 1e-6f);
    const float mx = focal * x / zc + 0.5f * IMG_W;
    const float my = focal * y / zc + 0.5f * IMG_H;

    const float c00 = cov[9*i+0], c01 = cov[9*i+1], c02 = cov[9*i+2];
    const float c10 = cov[9*i+3], c11 = cov[9*i+4], c12 = cov[9*i+5];
    const float c20 = cov[9*i+6], c21 = cov[9*i+7], c22 = cov[9*i+8];
    const float s00 = c00, s01 = 0.5f*(c01+c10), s02 = 0.5f*(c02+c20);
    const float s11 = c11, s12 = 0.5f*(c12+c21), s22 = c22;

    const float RS00 = R00*s00 + R01*s01 + R02*s02;
    const float RS01 = R00*s01 + R01*s11 + R02*s12;
    const float RS02 = R00*s02 + R01*s12 + R02*s22;
    const float RS10 = R10*s00 + R11*s01 + R12*s02;
    const float RS11 = R10*s01 + R11*s11 + R12*s12;
    const float RS12 = R10*s02 + R11*s12 + R12*s22;
    const float RS20 = R20*s00 + R21*s01 + R22*s02;
    const float RS21 = R20*s01 + R21*s11 + R22*s12;
    const float RS22 = R20*s02 + R21*s12 + R22*s22;
    const float CC00 = RS00*R00 + RS01*R01 + RS02*R02;
    const float CC01 = RS00*R10 + RS01*R11 + RS02*R12;
    const float CC02 = RS00*R20 + RS01*R21 + RS02*R22;
    const float CC11 = RS10*R10 + RS11*R11 + RS12*R12;
    const float CC12 = RS10*R20 + RS11*R21 + RS12*R22;
    const float CC20 = RS20*R00 + RS21*R01 + RS22*R02;
    const float CC21 = RS20*R10 + RS21*R11 + RS22*R12;
    const float CC22 = RS20*R20 + RS21*R21 + RS22*R22;

    const float j00 = focal / zc, j02 = -focal * x / (zc*zc);
    const float j11 = focal / zc, j12 = -focal * y / (zc*zc);

    const float v00 = CC00*j00 + CC02*j02;
    const float v02 = CC20*j00 + CC22*j02;
    const float v10 = CC01*j11 + CC02*j12;
    const float v11 = CC11*j11 + CC12*j12;
    const float v12 = CC21*j11 + CC22*j12;

    const float a  = j00*v00 + j02*v02 + 0.3f;   // cov2d00 + 0.3
    const float b  = j00*v10 + j02*v12;
    const float cQ = j11*v11 + j12*v12 + 0.3f;   // cov2d11 + 0.3

    const float det = a*cQ - b*b;
    const float det_safe = (det > 0.f) ? det : 1.f;
    const float conA =  cQ / det_safe;
    const float conB = -b  / det_safe;
    const float conC =  a  / det_safe;

    const bool  valid  = (z > 0.2f) && (det > 0.f);
    const float op_eff = valid ? opa[i] : 0.f;

    float dxm, dym;
    if (op_eff * 255.f > 1.f) {
        const float sN = logf(255.f * op_eff);         // > 0
        dxm = sqrtf(2.f * sN * a)  * 1.001f + 0.06f;   // conservative outward
        dym = sqrtf(2.f * sN * cQ) * 1.001f + 0.06f;
    } else {
        dxm = -1e30f; dym = -1e30f;                    // never visible
    }

    r0 = make_float4(mx, my, -0.5f*conA*LOG2E, -conB*LOG2E);
    r1 = make_float4(-0.5f*conC*LOG2E, op_eff, col[3*i], col[3*i+1]);
    r2 = col[3*i+2];
    r3 = make_float4(mx, my, dxm, dym);
}

// ---------------------------------------------------------------------------
// Kernel 1: fused project + stable rank-sort + scatter (16 blocks x 64).
// ---------------------------------------------------------------------------
__global__ __launch_bounds__(64) void gs_prep(
    const float* __restrict__ pos, const float* __restrict__ cov,
    const float* __restrict__ col, const float* __restrict__ opa,
    const float* __restrict__ cm,
    float4* __restrict__ g0, float4* __restrict__ g1, float* __restrict__ g2,
    float4* __restrict__ g3)
{
    __shared__ float4 zsh4[NG / 4];
    float* zsh = (float*)zsh4;

    const int tid = threadIdx.x;
    const float R20 = cm[8], R21 = cm[9], R22 = cm[10], T2 = cm[11];

    #pragma unroll
    for (int q = 0; q < NG / 64; ++q) {
        const int g = q * 64 + tid;
        zsh[g] = R20*pos[3*g] + R21*pos[3*g+1] + R22*pos[3*g+2] + T2;
    }
    __syncthreads();

    const int i = blockIdx.x * 64 + tid;
    float4 r0, r1, r3; float r2;
    project_one(i, pos, cov, col, opa, cm, r0, r1, r2, r3);

    const float zi = zsh[i];
    int rank = 0;
    #pragma unroll 4
    for (int j4 = 0; j4 < NG / 4; ++j4) {
        const float4 v = zsh4[j4];
        const int j = 4 * j4;
        rank += (v.x < zi || (v.x == zi && j + 0 < i)) ? 1 : 0;
        rank += (v.y < zi || (v.y == zi && j + 1 < i)) ? 1 : 0;
        rank += (v.z < zi || (v.z == zi && j + 2 < i)) ? 1 : 0;
        rank += (v.w < zi || (v.w == zi && j + 3 < i)) ? 1 : 0;
    }
    g0[rank] = r0; g1[rank] = r1; g2[rank] = r2; g3[rank] = r3;
}

// ---------------------------------------------------------------------------
// Kernel 2: LDS-resident, wave-uniform-culled tile raster + fused combine.
// 256 blocks x 1024 threads, 1 block/CU. Block = one 8x8 tile; wave w owns
// sorted chunk [64w, 64w+64); lane = pixel. All records staged once in LDS
// (proven: removes L1 latency -> VALU-bound). All per-gaussian LDS reads are
// wave-uniform broadcasts (conflict-free; fixes r8's 6.3M conflict cycles).
// Exact AABB cull (wave-coherent branch) skips ~85-90% of gaussians.
// 16 partials per pixel in 4 KB LDS; 16-step scan fuses the combine.
// ---------------------------------------------------------------------------
__global__ __launch_bounds__(1024) void gs_raster_tile(
    const float4* __restrict__ g0, const float4* __restrict__ g1,
    const float*  __restrict__ g2, const float4* __restrict__ g3,
    float* __restrict__ out)
{
    __shared__ float4 s0[NG];            // 16 KB
    __shared__ float4 s1[NG];            // 16 KB
    __shared__ float  s2[NG];            //  4 KB
    __shared__ float4 s3[NG];            // 16 KB
    __shared__ float4 part[16][64];      //  4 KB [chunk][pixel]

    const int tid = threadIdx.x;
    s0[tid] = g0[tid];
    s1[tid] = g1[tid];
    s2[tid] = g2[tid];
    s3[tid] = g3[tid];
    __syncthreads();

    const int w    = tid >> 6;           // wave = chunk 0..15 (64 gaussians)
    const int lane = tid & 63;           // pixel in 8x8 tile
    const int tile = blockIdx.x;         // 16x16 tiles
    const float tx0 = (float)((tile & 15) << 3);
    const float ty0 = (float)((tile >> 4) << 3);

    const float pxf = tx0 + (float)(lane & 7) + 0.5f;
    const float pyf = ty0 + (float)(lane >> 3) + 0.5f;
    const float txl = tx0 + 0.5f, txh = tx0 + 7.5f;
    const float tyl = ty0 + 0.5f, tyh = ty0 + 7.5f;

    float T = 1.f, cr = 0.f, cg = 0.f, cb = 0.f;
    const int base = w * 64;

    for (int i = 0; i < 64; ++i) {
        const float4 cull = s3[base + i];          // wave-uniform broadcast
        const bool hit = (cull.x - cull.z <= txh) && (cull.x + cull.z >= txl)
                      && (cull.y - cull.w <= tyh) && (cull.y + cull.w >= tyl);
        if (hit) {                                  // wave-coherent branch
            const float4 A = s0[base + i];          // uniform broadcast
            const float4 B = s1[base + i];
            const float  C = s2[base + i];
            const float dx = pxf - A.x;
            const float dy = pyf - A.y;
            const float pw = fminf(A.z*dx*dx + B.x*dy*dy + A.w*(dx*dy), 0.f);
            const float G = __builtin_amdgcn_exp2f(pw);
            float alpha = fminf(B.y * G, 0.99f);
            alpha = (alpha >= MIN_A) ? alpha : 0.f;
            const float wT = alpha * T;
            cr = fmaf(wT, B.z, cr);
            cg = fmaf(wT, B.w, cg);
            cb = fmaf(wT, C,   cb);
            T *= (1.f - alpha);
        }
    }

    part[w][lane] = make_float4(cr, cg, cb, T);
    __syncthreads();

    if (tid < 64) {                      // one thread per pixel: 16-chunk scan
        float Ts = 1.f, r = 0.f, g = 0.f, b = 0.f;
        #pragma unroll
        for (int k = 0; k < 16; ++k) {
            const float4 v = part[k][tid];
            r = fmaf(Ts, v.x, r);
            g = fmaf(Ts, v.y, g);
            b = fmaf(Ts, v.z, b);
            Ts *= v.w;
        }
        const int px = (int)tx0 + (tid & 7);
        const int py = (int)ty0 + (tid >> 3);
        float* o = out + 3 * (py * IMG_W + px);
        o[0] = r; o[1] = g; o[2] = b;
    }
}

// ---------------------------------------------------------------------------
extern "C" void kernel_launch(void* const* d_in, const int* in_sizes, int n_in,
                              void* d_out, int out_size, void* d_ws, size_t ws_size,
                              hipStream_t stream) {
    const float* pos = (const float*)d_in[0];
    const float* cov = (const float*)d_in[1];
    const float* col = (const float*)d_in[2];
    const float* opa = (const float*)d_in[3];
    const float* cm  = (const float*)d_in[4];

    char* ws = (char*)d_ws;
    float4* g0 = (float4*)(ws);                 // 16384 B
    float4* g1 = (float4*)(ws + 16384);         // 16384 B
    float*  g2 = (float*) (ws + 32768);         //  4096 B
    float4* g3 = (float4*)(ws + 36864);         // 16384 B

    gs_prep<<<NG / 64, 64, 0, stream>>>(pos, cov, col, opa, cm, g0, g1, g2, g3);
    gs_raster_tile<<<256, 1024, 0, stream>>>(g0, g1, g2, g3, (float*)d_out);
}